// Round 5
// baseline (196.808 us; speedup 1.0000x reference)
//
#include <hip/hip_runtime.h>
#include <math.h>

#define HEADS 4
#define DIMH  128
#define NB    16
#define CIN   512
#define SEQ   1024
#define OTOT  1536
#define KQ    (CIN / 8)

typedef __attribute__((ext_vector_type(8)))  short bf16x8;
typedef __attribute__((ext_vector_type(4)))  short bf16x4;
typedef __attribute__((ext_vector_type(4)))  float f32x4;
typedef __attribute__((ext_vector_type(16))) float f32x16;

#define MFMA16(a,b,c) __builtin_amdgcn_mfma_f32_16x16x32_bf16(a,b,c,0,0,0)
#define MFMA32(a,b,c) __builtin_amdgcn_mfma_f32_32x32x16_bf16(a,b,c,0,0,0)

__device__ __forceinline__ short f2bf(float f) {           // RNE
    unsigned u = __builtin_bit_cast(unsigned, f);
    u = (u + 0x7FFFu + ((u >> 16) & 1u)) >> 16;
    return (short)u;
}
// pack hi16(lo), hi16(hi) -> one dword {hi_bf16, lo_bf16} (truncating bf16)
__device__ __forceinline__ unsigned pk2(float lo, float hi) {
    return __builtin_amdgcn_perm(__builtin_bit_cast(unsigned, hi),
                                 __builtin_bit_cast(unsigned, lo), 0x07060302u);
}
union PF8 { unsigned u[4]; bf16x8 v; };

// ---------- convert fmap [b][c][s] fp32 -> FT2 [b][kq][s][8] bf16 ----------
__global__ __launch_bounds__(256) void convert_fmap(const float* __restrict__ F,
                                                    short* __restrict__ FT2) {
    const int s  = blockIdx.x * 256 + threadIdx.x;
    const int kq = blockIdx.y, b = blockIdx.z;
    const float* src = F + ((size_t)b * CIN + kq * 8) * SEQ + s;
    float v[8];
    #pragma unroll
    for (int i = 0; i < 8; ++i) v[i] = src[(size_t)i * SEQ];
    bf16x8 pk = { f2bf(v[0]), f2bf(v[1]), f2bf(v[2]), f2bf(v[3]),
                  f2bf(v[4]), f2bf(v[5]), f2bf(v[6]), f2bf(v[7]) };
    *(bf16x8*)&FT2[(((size_t)b * KQ + kq) * SEQ + s) * 8] = pk;
}

// ---------- convert w [o][c] fp32 -> Wb2 [kq][o][8] bf16 ----------
__global__ __launch_bounds__(256) void convert_w(const float* __restrict__ W,
                                                 short* __restrict__ Wb2) {
    const int o  = blockIdx.x * 256 + threadIdx.x;
    const int kq = blockIdx.y;
    float4 v0 = *(const float4*)&W[(size_t)o * CIN + kq * 8];
    float4 v1 = *(const float4*)&W[(size_t)o * CIN + kq * 8 + 4];
    bf16x8 pk = { f2bf(v0.x), f2bf(v0.y), f2bf(v0.z), f2bf(v0.w),
                  f2bf(v1.x), f2bf(v1.y), f2bf(v1.z), f2bf(v1.w) };
    *(bf16x8*)&Wb2[((size_t)kq * OTOT + o) * 8] = pk;
}

// ---------- QKV GEMM: LDS-free, 2-deep register pipeline ----------
// Q -> [bh][s][d]; K -> Kf[bh][c/8][s][8] (+emb); V -> Vf[bh][s/16][d][slot]
__global__ __launch_bounds__(256, 3) void qkv_gemm(
    const short* __restrict__ Wb2, const short* __restrict__ FT2,
    const float* __restrict__ height, const float* __restrict__ width,
    short* __restrict__ Qo, short* __restrict__ Kfo, short* __restrict__ Vfo)
{
    const int b = blockIdx.z, o0 = blockIdx.y * 128, s0 = blockIdx.x * 128;
    const int t = threadIdx.x, l = t & 63, w = t >> 6;
    const int quad = l >> 4, ln = l & 15;
    const int wrow = (w >> 1) * 64, wcol = (w & 1) * 64;

    const short* Ap = Wb2 + (((size_t)quad * OTOT) + (o0 + wrow + ln)) * 8;
    const short* Bp = FT2 + ((((size_t)b * KQ + quad) * SEQ) + (s0 + wcol + ln)) * 8;

    f32x4 acc[4][4] = {};
    bf16x8 a0[4], b0[4], a1[4], b1[4];

#define GLOADF(ks, af, bfr) { \
    const short* ga = Ap + (size_t)(ks) * 4 * OTOT * 8; \
    const short* gb = Bp + (size_t)(ks) * 4 * SEQ * 8; \
    _Pragma("unroll") for (int i = 0; i < 4; ++i) af[i]  = *(const bf16x8*)(ga + (size_t)i * 16 * 8); \
    _Pragma("unroll") for (int j = 0; j < 4; ++j) bfr[j] = *(const bf16x8*)(gb + (size_t)j * 16 * 8); }
#define COMP(af, bfr) { \
    _Pragma("unroll") for (int i = 0; i < 4; ++i) \
        _Pragma("unroll") for (int j = 0; j < 4; ++j) \
            acc[i][j] = MFMA16(af[i], bfr[j], acc[i][j]); }

    GLOADF(0, a0, b0);
    GLOADF(1, a1, b1);
    for (int ks = 0; ks < 16; ks += 2) {
        COMP(a0, b0);
        if (ks + 2 < 16) GLOADF(ks + 2, a0, b0);
        COMP(a1, b1);
        if (ks + 3 < 16) GLOADF(ks + 3, a1, b1);
    }

    const int sec = o0 >> 9;
    const int h   = (o0 >> 7) & 3;
    const size_t bh = (size_t)b * HEADS + h;

    if (sec == 0) {
        const float qs = 0.08838834764831845f * 1.4426950408889634f; // scale*log2(e)
        #pragma unroll
        for (int ti = 0; ti < 4; ++ti) {
            int d = wrow + ti * 16 + quad * 4;
            #pragma unroll
            for (int tj = 0; tj < 4; ++tj) {
                int s = s0 + wcol + tj * 16 + ln;
                f32x4 a = acc[ti][tj];
                bf16x4 pk4 = { f2bf(a[0]*qs), f2bf(a[1]*qs), f2bf(a[2]*qs), f2bf(a[3]*qs) };
                *(bf16x4*)&Qo[(bh * SEQ + s) * DIMH + d] = pk4;
            }
        }
    } else if (sec == 1) {
        #pragma unroll
        for (int ti = 0; ti < 4; ++ti) {
            int d = wrow + ti * 16 + quad * 4;
            #pragma unroll
            for (int tj = 0; tj < 4; ++tj) {
                int s = s0 + wcol + tj * 16 + ln;
                float4 hv = *(const float4*)&height[(size_t)(s >> 5) * DIMH + d];
                float4 wv = *(const float4*)&width[(size_t)(s & 31) * DIMH + d];
                f32x4 a = acc[ti][tj];
                bf16x4 pk4 = { f2bf(a[0] + hv.x + wv.x), f2bf(a[1] + hv.y + wv.y),
                               f2bf(a[2] + hv.z + wv.z), f2bf(a[3] + hv.w + wv.w) };
                // Kf[bh][d>>3][s][d&7]  (d&7 in {0,4} -> aligned b64 store)
                *(bf16x4*)&Kfo[(((size_t)bh * 16 + (d >> 3)) * SEQ + s) * 8 + (d & 7)] = pk4;
            }
        }
    } else {
        const int slot = ((ln >> 2) & 1) * 8 + (ln & 3) + ((ln >> 3) << 2);
        #pragma unroll
        for (int ti = 0; ti < 4; ++ti) {
            int d = wrow + ti * 16 + quad * 4;
            #pragma unroll
            for (int tj = 0; tj < 4; ++tj) {
                int s = s0 + wcol + tj * 16 + ln;
                size_t vb = (((size_t)bh * 64 + (s >> 4)) * DIMH) * 16 + slot;
                f32x4 a = acc[ti][tj];
                #pragma unroll
                for (int r = 0; r < 4; ++r)
                    Vfo[vb + (size_t)(d + r) * 16] = f2bf(a[r]);
            }
        }
    }
}

// ---------- flash attention: S^T trick, P stays in registers, V direct-global ----------
#define BQ 128
#define BJ 64
#define KSTR 136   // proven conflict-free stride (r4: SQ_LDS_BANK_CONFLICT = 0)

__global__ __launch_bounds__(256, 2) void attn(
    const short* __restrict__ Q, const short* __restrict__ Kf,
    const short* __restrict__ Vf, float* __restrict__ out)
{
    __shared__ short Ks[2 * BJ * KSTR];   // double-buffered K tile [j][c]

    const int t = threadIdx.x, l = t & 63, w = t >> 6;
    const int h = l >> 5, c31 = l & 31;

    const int L = blockIdx.x;
    const int x = L & 7, inner = L >> 3;          // XCD swizzle: same bh -> same XCD
    const int bh = x * 8 + (inner >> 3);
    const int q0 = (inner & 7) * BQ;
    const size_t obase = (size_t)bh * DIMH * SEQ;

    // Q B-fragments (n = i = q0+w*32+c31, k = c = kc*16 + h*8 + 0..7)
    bf16x8 qf[8];
    {
        const short* Qp = Q + ((size_t)bh * SEQ + (q0 + w * 32 + c31)) * DIMH + h * 8;
        #pragma unroll
        for (int kc = 0; kc < 8; ++kc)
            qf[kc] = *(const bf16x8*)(Qp + kc * 16);
    }

    PF8 ones;
    ones.u[0] = ones.u[1] = ones.u[2] = ones.u[3] = 0x3F803F80u;  // bf16 1.0 pairs

    const short* Kg = Kf + (size_t)bh * 16 * SEQ * 8;     // [cg][s][8]
    const short* Vlane = Vf + (size_t)bh * 64 * (DIMH * 16) + (c31 * 16 + h * 8);

    f32x16 O[4] = {};
    f32x16 Lacc = {};

    // prologue: stage K tile 0
    {
        int4 kreg[4];
        #pragma unroll
        for (int p = 0; p < 4; ++p)
            kreg[p] = *(const int4*)(Kg + ((size_t)(p * 4 + w) * SEQ + l) * 8);
        #pragma unroll
        for (int p = 0; p < 4; ++p)
            *(int4*)&Ks[l * KSTR + (p * 4 + w) * 8] = kreg[p];
    }
    __syncthreads();

    for (int ti = 0; ti < 16; ++ti) {
        const int cur = (ti & 1) * (BJ * KSTR);
        const int nxt = (BJ * KSTR) - cur;
        int4 kreg[4];
        if (ti < 15) {                                  // prefetch next K tile
            const int j0n = (ti + 1) * BJ;
            #pragma unroll
            for (int p = 0; p < 4; ++p)
                kreg[p] = *(const int4*)(Kg + ((size_t)(p * 4 + w) * SEQ + j0n + l) * 8);
        }

        // S^T = K * Q^T : lane holds P[i = own][j patterns]
        f32x16 S0 = {}, S1 = {};
        #pragma unroll
        for (int kc = 0; kc < 8; ++kc) {
            bf16x8 k0 = *(const bf16x8*)&Ks[cur + c31 * KSTR + kc * 16 + h * 8];
            bf16x8 k1 = *(const bf16x8*)&Ks[cur + (32 + c31) * KSTR + kc * 16 + h * 8];
            S0 = MFMA32(k0, qf[kc], S0);
            S1 = MFMA32(k1, qf[kc], S1);
        }

        // exp2 -> packed bf16 P-fragments (register-only); l-sum via ones-MFMA
        const int jgb = ti * 4;
        #pragma unroll
        for (int half = 0; half < 2; ++half) {
            const f32x16& S = half ? S1 : S0;
            #pragma unroll
            for (int kk = 0; kk < 2; ++kk) {
                PF8 pf;
                #pragma unroll
                for (int m = 0; m < 4; ++m) {
                    float a = __builtin_amdgcn_exp2f(S[kk * 8 + 2 * m]);
                    float b = __builtin_amdgcn_exp2f(S[kk * 8 + 2 * m + 1]);
                    pf.u[m] = pk2(a, b);
                }
                Lacc = MFMA32(ones.v, pf.v, Lacc);
                const short* vp = Vlane + (size_t)(jgb + half * 2 + kk) * (DIMH * 16);
                #pragma unroll
                for (int dc = 0; dc < 4; ++dc) {
                    bf16x8 vf = *(const bf16x8*)(vp + dc * 32 * 16);
                    O[dc] = MFMA32(vf, pf.v, O[dc]);
                }
            }
        }

        if (ti < 15) {
            #pragma unroll
            for (int p = 0; p < 4; ++p)
                *(int4*)&Ks[nxt + l * KSTR + (p * 4 + w) * 8] = kreg[p];
        }
        __syncthreads();
    }

    // epilogue: every Lacc row = full row-sum for i = c31 (both h halves)
    float linv = 1.0f / Lacc[0];
    #pragma unroll
    for (int dc = 0; dc < 4; ++dc)
        #pragma unroll
        for (int r = 0; r < 16; ++r) {
            int d = dc * 32 + (r & 3) + 8 * (r >> 2) + 4 * h;
            out[obase + (size_t)d * SEQ + q0 + w * 32 + c31] = O[dc][r] * linv;
        }
}

extern "C" void kernel_launch(void* const* d_in, const int* in_sizes, int n_in,
                              void* d_out, int out_size, void* d_ws, size_t ws_size,
                              hipStream_t stream) {
    const float* fmap   = (const float*)d_in[0];
    const float* w_qkv  = (const float*)d_in[1];
    const float* height = (const float*)d_in[2];
    const float* width  = (const float*)d_in[3];
    float* outp = (float*)d_out;

    const size_t n_ft  = (size_t)NB * SEQ * CIN;
    const size_t n_w   = (size_t)OTOT * CIN;
    const size_t n_qkv = (size_t)NB * HEADS * SEQ * DIMH;

    short* FT2 = (short*)d_ws;
    short* Wb2 = FT2 + n_ft;
    short* Qb  = Wb2 + n_w;
    short* Kfb = Qb + n_qkv;
    short* Vfb = Kfb + n_qkv;

    convert_fmap<<<dim3(SEQ / 256, KQ, NB), 256, 0, stream>>>(fmap, FT2);
    convert_w<<<dim3(OTOT / 256, KQ), 256, 0, stream>>>(w_qkv, Wb2);
    qkv_gemm<<<dim3(SEQ / 128, OTOT / 128, NB), 256, 0, stream>>>(
        Wb2, FT2, height, width, Qb, Kfb, Vfb);
    attn<<<dim3(NB * HEADS * (SEQ / BQ)), 256, 0, stream>>>(Qb, Kfb, Vfb, outp);
}

// Round 6
// 176.531 us; speedup vs baseline: 1.1149x; 1.1149x over previous
//
#include <hip/hip_runtime.h>
#include <math.h>

#define HEADS 4
#define DIMH  128
#define NB    16
#define CIN   512
#define SEQ   1024
#define OTOT  1536
#define KQ    (CIN / 8)

typedef __attribute__((ext_vector_type(8)))  short bf16x8;
typedef __attribute__((ext_vector_type(4)))  short bf16x4;
typedef __attribute__((ext_vector_type(4)))  float f32x4;
typedef __attribute__((ext_vector_type(16))) float f32x16;

#define MFMA16(a,b,c) __builtin_amdgcn_mfma_f32_16x16x32_bf16(a,b,c,0,0,0)
#define MFMA32(a,b,c) __builtin_amdgcn_mfma_f32_32x32x16_bf16(a,b,c,0,0,0)

__device__ __forceinline__ short f2bf(float f) {           // RNE
    unsigned u = __builtin_bit_cast(unsigned, f);
    u = (u + 0x7FFFu + ((u >> 16) & 1u)) >> 16;
    return (short)u;
}
// pack hi16(lo), hi16(hi) -> one dword {hi_bf16, lo_bf16} (truncating bf16)
__device__ __forceinline__ unsigned pk2(float lo, float hi) {
    return __builtin_amdgcn_perm(__builtin_bit_cast(unsigned, hi),
                                 __builtin_bit_cast(unsigned, lo), 0x07060302u);
}
union PF8 { unsigned u[4]; bf16x8 v; };

// ---------- convert fmap [b][c][s] fp32 -> FT2 [b][kq][s][8] bf16 ----------
__global__ __launch_bounds__(256) void convert_fmap(const float* __restrict__ F,
                                                    short* __restrict__ FT2) {
    const int s  = blockIdx.x * 256 + threadIdx.x;
    const int kq = blockIdx.y, b = blockIdx.z;
    const float* src = F + ((size_t)b * CIN + kq * 8) * SEQ + s;
    float v[8];
    #pragma unroll
    for (int i = 0; i < 8; ++i) v[i] = src[(size_t)i * SEQ];
    bf16x8 pk = { f2bf(v[0]), f2bf(v[1]), f2bf(v[2]), f2bf(v[3]),
                  f2bf(v[4]), f2bf(v[5]), f2bf(v[6]), f2bf(v[7]) };
    *(bf16x8*)&FT2[(((size_t)b * KQ + kq) * SEQ + s) * 8] = pk;
}

// ---------- convert w [o][c] fp32 -> Wb2 [kq][o][8] bf16 ----------
__global__ __launch_bounds__(256) void convert_w(const float* __restrict__ W,
                                                 short* __restrict__ Wb2) {
    const int o  = blockIdx.x * 256 + threadIdx.x;
    const int kq = blockIdx.y;
    float4 v0 = *(const float4*)&W[(size_t)o * CIN + kq * 8];
    float4 v1 = *(const float4*)&W[(size_t)o * CIN + kq * 8 + 4];
    bf16x8 pk = { f2bf(v0.x), f2bf(v0.y), f2bf(v0.z), f2bf(v0.w),
                  f2bf(v1.x), f2bf(v1.y), f2bf(v1.z), f2bf(v1.w) };
    *(bf16x8*)&Wb2[((size_t)kq * OTOT + o) * 8] = pk;
}

// ---------- QKV GEMM: LDS-free, 2-deep register pipeline, XCD-locality swizzle ----------
// Q -> [bh][s][d]; K -> Kf[bh][c/8][s][8] (+emb); V -> Vf[bh][s/16][d][slot]
__global__ __launch_bounds__(256, 3) void qkv_gemm(
    const short* __restrict__ Wb2, const short* __restrict__ FT2,
    const float* __restrict__ height, const float* __restrict__ width,
    short* __restrict__ Qo, short* __restrict__ Kfo, short* __restrict__ Vfo)
{
    // swizzle: all 12 o-blocks of one (b, s-range) land on one XCD (L%8) so the
    // shared B-tile is served from that XCD's L2 after the first toucher.
    const int L  = blockIdx.x;
    const int x8 = L & 7, m = L >> 3;
    const int g  = x8 + 8 * (m / 12);      // 128 groups = (b, sx)
    const int oy = m % 12;
    const int b  = g >> 3, sx = g & 7;
    const int o0 = oy * 128, s0 = sx * 128;

    const int t = threadIdx.x, l = t & 63, w = t >> 6;
    const int quad = l >> 4, ln = l & 15;
    const int wrow = (w >> 1) * 64, wcol = (w & 1) * 64;

    const short* Ap = Wb2 + (((size_t)quad * OTOT) + (o0 + wrow + ln)) * 8;
    const short* Bp = FT2 + ((((size_t)b * KQ + quad) * SEQ) + (s0 + wcol + ln)) * 8;

    f32x4 acc[4][4] = {};
    bf16x8 a0[4], b0[4], a1[4], b1[4];

#define GLOADF(ks, af, bfr) { \
    const short* ga = Ap + (size_t)(ks) * 4 * OTOT * 8; \
    const short* gb = Bp + (size_t)(ks) * 4 * SEQ * 8; \
    _Pragma("unroll") for (int i = 0; i < 4; ++i) af[i]  = *(const bf16x8*)(ga + (size_t)i * 16 * 8); \
    _Pragma("unroll") for (int j = 0; j < 4; ++j) bfr[j] = *(const bf16x8*)(gb + (size_t)j * 16 * 8); }
#define COMP(af, bfr) { \
    _Pragma("unroll") for (int i = 0; i < 4; ++i) \
        _Pragma("unroll") for (int j = 0; j < 4; ++j) \
            acc[i][j] = MFMA16(af[i], bfr[j], acc[i][j]); }

    GLOADF(0, a0, b0);
    GLOADF(1, a1, b1);
    for (int ks = 0; ks < 16; ks += 2) {
        COMP(a0, b0);
        if (ks + 2 < 16) GLOADF(ks + 2, a0, b0);
        COMP(a1, b1);
        if (ks + 3 < 16) GLOADF(ks + 3, a1, b1);
    }

    const int sec = o0 >> 9;
    const int h   = (o0 >> 7) & 3;
    const size_t bh = (size_t)b * HEADS + h;

    if (sec == 0) {
        const float qs = 0.08838834764831845f * 1.4426950408889634f; // scale*log2(e)
        #pragma unroll
        for (int ti = 0; ti < 4; ++ti) {
            int d = wrow + ti * 16 + quad * 4;
            #pragma unroll
            for (int tj = 0; tj < 4; ++tj) {
                int s = s0 + wcol + tj * 16 + ln;
                f32x4 a = acc[ti][tj];
                bf16x4 pk4 = { f2bf(a[0]*qs), f2bf(a[1]*qs), f2bf(a[2]*qs), f2bf(a[3]*qs) };
                *(bf16x4*)&Qo[(bh * SEQ + s) * DIMH + d] = pk4;
            }
        }
    } else if (sec == 1) {
        #pragma unroll
        for (int ti = 0; ti < 4; ++ti) {
            int d = wrow + ti * 16 + quad * 4;
            #pragma unroll
            for (int tj = 0; tj < 4; ++tj) {
                int s = s0 + wcol + tj * 16 + ln;
                float4 hv = *(const float4*)&height[(size_t)(s >> 5) * DIMH + d];
                float4 wv = *(const float4*)&width[(size_t)(s & 31) * DIMH + d];
                f32x4 a = acc[ti][tj];
                bf16x4 pk4 = { f2bf(a[0] + hv.x + wv.x), f2bf(a[1] + hv.y + wv.y),
                               f2bf(a[2] + hv.z + wv.z), f2bf(a[3] + hv.w + wv.w) };
                // Kf[bh][d>>3][s][d&7]  (d&7 in {0,4} -> aligned b64 store)
                *(bf16x4*)&Kfo[(((size_t)bh * 16 + (d >> 3)) * SEQ + s) * 8 + (d & 7)] = pk4;
            }
        }
    } else {
        const int slot = ((ln >> 2) & 1) * 8 + (ln & 3) + ((ln >> 3) << 2);
        #pragma unroll
        for (int ti = 0; ti < 4; ++ti) {
            int d = wrow + ti * 16 + quad * 4;
            #pragma unroll
            for (int tj = 0; tj < 4; ++tj) {
                int s = s0 + wcol + tj * 16 + ln;
                size_t vb = (((size_t)bh * 64 + (s >> 4)) * DIMH) * 16 + slot;
                f32x4 a = acc[ti][tj];
                #pragma unroll
                for (int r = 0; r < 4; ++r)
                    Vfo[vb + (size_t)(d + r) * 16] = f2bf(a[r]);
            }
        }
    }
}

// ---------- flash attention: S^T trick, register P, top-of-tile V prefetch ----------
#define BQ 128
#define BJ 64
#define KSTR 136   // conflict-free stride (r4/r5: SQ_LDS_BANK_CONFLICT = 0)

__global__ __launch_bounds__(256, 2) void attn(
    const short* __restrict__ Q, const short* __restrict__ Kf,
    const short* __restrict__ Vf, float* __restrict__ out)
{
    __shared__ short Ks[2 * BJ * KSTR];   // double-buffered K tile [j][c]

    const int t = threadIdx.x, l = t & 63, w = t >> 6;
    const int h = l >> 5, c31 = l & 31;

    const int L = blockIdx.x;
    const int x = L & 7, inner = L >> 3;          // XCD swizzle: same bh -> same XCD
    const int bh = x * 8 + (inner >> 3);
    const int q0 = (inner & 7) * BQ;
    const size_t obase = (size_t)bh * DIMH * SEQ;

    // Q B-fragments (n = i = q0+w*32+c31, k = c = kc*16 + h*8 + 0..7)
    bf16x8 qf[8];
    {
        const short* Qp = Q + ((size_t)bh * SEQ + (q0 + w * 32 + c31)) * DIMH + h * 8;
        #pragma unroll
        for (int kc = 0; kc < 8; ++kc)
            qf[kc] = *(const bf16x8*)(Qp + kc * 16);
    }

    const short* Kg = Kf + (size_t)bh * 16 * SEQ * 8;             // [cg][s][8]
    const short* Vlane = Vf + (size_t)bh * 64 * (DIMH * 16) + (c31 * 16 + h * 8);

    f32x16 O[4] = {};
    float psum = 0.f;

    // prologue: stage K tile 0
    {
        int4 kreg[4];
        #pragma unroll
        for (int p = 0; p < 4; ++p)
            kreg[p] = *(const int4*)(Kg + ((size_t)(p * 4 + w) * SEQ + l) * 8);
        #pragma unroll
        for (int p = 0; p < 4; ++p)
            *(int4*)&Ks[l * KSTR + (p * 4 + w) * 8] = kreg[p];
    }
    __syncthreads();

    for (int ti = 0; ti < 16; ++ti) {
        const int cur = (ti & 1) * (BJ * KSTR);
        const int nxt = (BJ * KSTR) - cur;

        // (1) V prefetch FIRST (oldest vmcnt -> PV can wait on these while K stays in flight)
        bf16x8 vreg[4][4];
        {
            const short* vp0 = Vlane + (size_t)(ti * 4) * (DIMH * 16);
            #pragma unroll
            for (int gi = 0; gi < 4; ++gi)
                #pragma unroll
                for (int dc = 0; dc < 4; ++dc)
                    vreg[gi][dc] = *(const bf16x8*)(vp0 + (size_t)gi * (DIMH * 16) + dc * 32 * 16);
        }
        // (2) K(ti+1) prefetch into registers
        int4 kreg[4];
        if (ti < 15) {
            const int j0n = (ti + 1) * BJ;
            #pragma unroll
            for (int p = 0; p < 4; ++p)
                kreg[p] = *(const int4*)(Kg + ((size_t)(p * 4 + w) * SEQ + j0n + l) * 8);
        }

        // (3) S^T = K * Q^T : lane holds P[i = own i][32 j-values]
        f32x16 S0 = {}, S1 = {};
        #pragma unroll
        for (int kc = 0; kc < 8; ++kc) {
            bf16x8 k0 = *(const bf16x8*)&Ks[cur + c31 * KSTR + kc * 16 + h * 8];
            bf16x8 k1 = *(const bf16x8*)&Ks[cur + (32 + c31) * KSTR + kc * 16 + h * 8];
            S0 = MFMA32(k0, qf[kc], S0);
            S1 = MFMA32(k1, qf[kc], S1);
        }

        // (4) exp2 -> packed bf16 P-fragments; scalar psum; PV from prefetched vreg
        #pragma unroll
        for (int half = 0; half < 2; ++half) {
            const f32x16& S = half ? S1 : S0;
            #pragma unroll
            for (int kk = 0; kk < 2; ++kk) {
                PF8 pf;
                #pragma unroll
                for (int m = 0; m < 4; ++m) {
                    float a = __builtin_amdgcn_exp2f(S[kk * 8 + 2 * m]);
                    float b = __builtin_amdgcn_exp2f(S[kk * 8 + 2 * m + 1]);
                    psum += a + b;
                    pf.u[m] = pk2(a, b);
                }
                const int gi = half * 2 + kk;
                #pragma unroll
                for (int dc = 0; dc < 4; ++dc)
                    O[dc] = MFMA32(vreg[gi][dc], pf.v, O[dc]);
            }
        }

        // (5) commit next K tile to LDS, single barrier per tile
        if (ti < 15) {
            #pragma unroll
            for (int p = 0; p < 4; ++p)
                *(int4*)&Ks[nxt + l * KSTR + (p * 4 + w) * 8] = kreg[p];
        }
        __syncthreads();
    }

    // row sum: this lane holds half the j's for row i=c31; other half is in lane^32
    psum += __shfl_xor(psum, 32);
    float linv = 1.0f / psum;

    #pragma unroll
    for (int dc = 0; dc < 4; ++dc)
        #pragma unroll
        for (int r = 0; r < 16; ++r) {
            int d = dc * 32 + (r & 3) + 8 * (r >> 2) + 4 * h;
            out[obase + (size_t)d * SEQ + q0 + w * 32 + c31] = O[dc][r] * linv;
        }
}

extern "C" void kernel_launch(void* const* d_in, const int* in_sizes, int n_in,
                              void* d_out, int out_size, void* d_ws, size_t ws_size,
                              hipStream_t stream) {
    const float* fmap   = (const float*)d_in[0];
    const float* w_qkv  = (const float*)d_in[1];
    const float* height = (const float*)d_in[2];
    const float* width  = (const float*)d_in[3];
    float* outp = (float*)d_out;

    const size_t n_ft  = (size_t)NB * SEQ * CIN;
    const size_t n_w   = (size_t)OTOT * CIN;
    const size_t n_qkv = (size_t)NB * HEADS * SEQ * DIMH;

    short* FT2 = (short*)d_ws;
    short* Wb2 = FT2 + n_ft;
    short* Qb  = Wb2 + n_w;
    short* Kfb = Qb + n_qkv;
    short* Vfb = Kfb + n_qkv;

    convert_fmap<<<dim3(SEQ / 256, KQ, NB), 256, 0, stream>>>(fmap, FT2);
    convert_w<<<dim3(OTOT / 256, KQ), 256, 0, stream>>>(w_qkv, Wb2);
    qkv_gemm<<<dim3(8 * 12 * NB), 256, 0, stream>>>(
        Wb2, FT2, height, width, Qb, Kfb, Vfb);
    attn<<<dim3(NB * HEADS * (SEQ / BQ)), 256, 0, stream>>>(Qb, Kfb, Vfb, outp);
}

// Round 7
// 172.054 us; speedup vs baseline: 1.1439x; 1.0260x over previous
//
#include <hip/hip_runtime.h>
#include <math.h>

#define HEADS 4
#define DIMH  128
#define NB    16
#define CIN   512
#define SEQ   1024
#define OTOT  1536
#define KQ    (CIN / 8)

typedef __attribute__((ext_vector_type(8)))  short bf16x8;
typedef __attribute__((ext_vector_type(4)))  short bf16x4;
typedef __attribute__((ext_vector_type(4)))  float f32x4;
typedef __attribute__((ext_vector_type(16))) float f32x16;

#define MFMA16(a,b,c) __builtin_amdgcn_mfma_f32_16x16x32_bf16(a,b,c,0,0,0)
#define MFMA32(a,b,c) __builtin_amdgcn_mfma_f32_32x32x16_bf16(a,b,c,0,0,0)

__device__ __forceinline__ short f2bf(float f) {           // RNE
    unsigned u = __builtin_bit_cast(unsigned, f);
    u = (u + 0x7FFFu + ((u >> 16) & 1u)) >> 16;
    return (short)u;
}
// pack hi16(lo), hi16(hi) -> one dword {hi_bf16, lo_bf16} (truncating bf16)
__device__ __forceinline__ unsigned pk2(float lo, float hi) {
    return __builtin_amdgcn_perm(__builtin_bit_cast(unsigned, hi),
                                 __builtin_bit_cast(unsigned, lo), 0x07060302u);
}
union PF8 { unsigned u[4]; bf16x8 v; };

// ---------- merged converts: fmap -> FT2 [b][kq][s][8], w -> Wb2 [kq][o][8] ----------
__global__ __launch_bounds__(256) void convert_all(const float* __restrict__ F,
                                                   const float* __restrict__ W,
                                                   short* __restrict__ FT2,
                                                   short* __restrict__ Wb2) {
    const int kq = blockIdx.y;
    if (blockIdx.z == NB) {                       // weight part: x in [0,6)
        const int o = blockIdx.x * 256 + threadIdx.x;
        float4 v0 = *(const float4*)&W[(size_t)o * CIN + kq * 8];
        float4 v1 = *(const float4*)&W[(size_t)o * CIN + kq * 8 + 4];
        bf16x8 pk = { f2bf(v0.x), f2bf(v0.y), f2bf(v0.z), f2bf(v0.w),
                      f2bf(v1.x), f2bf(v1.y), f2bf(v1.z), f2bf(v1.w) };
        *(bf16x8*)&Wb2[((size_t)kq * OTOT + o) * 8] = pk;
        return;
    }
    if (blockIdx.x >= 4) return;                  // fmap part: x in [0,4)
    const int s = blockIdx.x * 256 + threadIdx.x;
    const int b = blockIdx.z;
    const float* src = F + ((size_t)b * CIN + kq * 8) * SEQ + s;
    float v[8];
    #pragma unroll
    for (int i = 0; i < 8; ++i) v[i] = src[(size_t)i * SEQ];
    bf16x8 pk = { f2bf(v[0]), f2bf(v[1]), f2bf(v[2]), f2bf(v[3]),
                  f2bf(v[4]), f2bf(v[5]), f2bf(v[6]), f2bf(v[7]) };
    *(bf16x8*)&FT2[(((size_t)b * KQ + kq) * SEQ + s) * 8] = pk;
}

// ---------- QKV GEMM: LDS-free, 2-deep register pipeline, XCD-locality swizzle ----------
// Q -> [bh][s][d]; K -> Kf[bh][c/8][s][8] (+emb); V -> Vf[bh][s/16][d][slot]
__global__ __launch_bounds__(256, 3) void qkv_gemm(
    const short* __restrict__ Wb2, const short* __restrict__ FT2,
    const float* __restrict__ height, const float* __restrict__ width,
    short* __restrict__ Qo, short* __restrict__ Kfo, short* __restrict__ Vfo)
{
    const int L  = blockIdx.x;
    const int x8 = L & 7, m = L >> 3;
    const int g  = x8 + 8 * (m / 12);      // 128 groups = (b, sx) pinned per XCD
    const int oy = m % 12;
    const int b  = g >> 3, sx = g & 7;
    const int o0 = oy * 128, s0 = sx * 128;

    const int t = threadIdx.x, l = t & 63, w = t >> 6;
    const int quad = l >> 4, ln = l & 15;
    const int wrow = (w >> 1) * 64, wcol = (w & 1) * 64;

    const short* Ap = Wb2 + (((size_t)quad * OTOT) + (o0 + wrow + ln)) * 8;
    const short* Bp = FT2 + ((((size_t)b * KQ + quad) * SEQ) + (s0 + wcol + ln)) * 8;

    f32x4 acc[4][4] = {};
    bf16x8 a0[4], b0[4], a1[4], b1[4];

#define GLOADF(ks, af, bfr) { \
    const short* ga = Ap + (size_t)(ks) * 4 * OTOT * 8; \
    const short* gb = Bp + (size_t)(ks) * 4 * SEQ * 8; \
    _Pragma("unroll") for (int i = 0; i < 4; ++i) af[i]  = *(const bf16x8*)(ga + (size_t)i * 16 * 8); \
    _Pragma("unroll") for (int j = 0; j < 4; ++j) bfr[j] = *(const bf16x8*)(gb + (size_t)j * 16 * 8); }
#define COMP(af, bfr) { \
    _Pragma("unroll") for (int i = 0; i < 4; ++i) \
        _Pragma("unroll") for (int j = 0; j < 4; ++j) \
            acc[i][j] = MFMA16(af[i], bfr[j], acc[i][j]); }

    GLOADF(0, a0, b0);
    GLOADF(1, a1, b1);
    for (int ks = 0; ks < 16; ks += 2) {
        COMP(a0, b0);
        if (ks + 2 < 16) GLOADF(ks + 2, a0, b0);
        COMP(a1, b1);
        if (ks + 3 < 16) GLOADF(ks + 3, a1, b1);
    }

    const int sec = o0 >> 9;
    const int h   = (o0 >> 7) & 3;
    const size_t bh = (size_t)b * HEADS + h;

    if (sec == 0) {
        const float qs = 0.08838834764831845f * 1.4426950408889634f; // scale*log2(e)
        #pragma unroll
        for (int ti = 0; ti < 4; ++ti) {
            int d = wrow + ti * 16 + quad * 4;
            #pragma unroll
            for (int tj = 0; tj < 4; ++tj) {
                int s = s0 + wcol + tj * 16 + ln;
                f32x4 a = acc[ti][tj];
                bf16x4 pk4 = { f2bf(a[0]*qs), f2bf(a[1]*qs), f2bf(a[2]*qs), f2bf(a[3]*qs) };
                *(bf16x4*)&Qo[(bh * SEQ + s) * DIMH + d] = pk4;
            }
        }
    } else if (sec == 1) {
        #pragma unroll
        for (int ti = 0; ti < 4; ++ti) {
            int d = wrow + ti * 16 + quad * 4;
            #pragma unroll
            for (int tj = 0; tj < 4; ++tj) {
                int s = s0 + wcol + tj * 16 + ln;
                float4 hv = *(const float4*)&height[(size_t)(s >> 5) * DIMH + d];
                float4 wv = *(const float4*)&width[(size_t)(s & 31) * DIMH + d];
                f32x4 a = acc[ti][tj];
                bf16x4 pk4 = { f2bf(a[0] + hv.x + wv.x), f2bf(a[1] + hv.y + wv.y),
                               f2bf(a[2] + hv.z + wv.z), f2bf(a[3] + hv.w + wv.w) };
                *(bf16x4*)&Kfo[(((size_t)bh * 16 + (d >> 3)) * SEQ + s) * 8 + (d & 7)] = pk4;
            }
        }
    } else {
        const int slot = ((ln >> 2) & 1) * 8 + (ln & 3) + ((ln >> 3) << 2);
        #pragma unroll
        for (int ti = 0; ti < 4; ++ti) {
            int d = wrow + ti * 16 + quad * 4;
            #pragma unroll
            for (int tj = 0; tj < 4; ++tj) {
                int s = s0 + wcol + tj * 16 + ln;
                size_t vb = (((size_t)bh * 64 + (s >> 4)) * DIMH) * 16 + slot;
                f32x4 a = acc[ti][tj];
                #pragma unroll
                for (int r = 0; r < 4; ++r)
                    Vfo[vb + (size_t)(d + r) * 16] = f2bf(a[r]);
            }
        }
    }
}

// ---------- flash attention: software-pipelined QK(t+1) || PV(t) ----------
#define BQ 128
#define BJ 64
#define KSTR 136   // conflict-free stride (r4-r6: SQ_LDS_BANK_CONFLICT = 0)

// invariant at iter ti: S0/S1 = S(ti); Ks slot[(ti+1)&1] = K(ti+1)
#define ATTN_ITER(ti, DO_QK, DO_PRE, DO_BAR)                                        \
{                                                                                   \
    const int rd = (((ti) + 1) & 1) * (BJ * KSTR);                                  \
    const int wr = ((ti) & 1) * (BJ * KSTR);                                        \
    const short* vp0 = Vlane + (size_t)((ti) * 4) * (DIMH * 16);                    \
    bf16x8 vr[4][4];                                                                \
    _Pragma("unroll") for (int gi = 0; gi < 2; ++gi)                                \
      _Pragma("unroll") for (int dc = 0; dc < 4; ++dc)                              \
        vr[gi][dc] = *(const bf16x8*)(vp0 + (size_t)gi * (DIMH * 16) + dc * 32 * 16);\
    int4 kreg[4];                                                                   \
    if (DO_PRE) {                                                                   \
        _Pragma("unroll") for (int p = 0; p < 4; ++p)                               \
            kreg[p] = *(const int4*)(Kg + ((size_t)(p * 4 + w) * SEQ + ((ti) + 2) * BJ + l) * 8); \
    }                                                                               \
    PF8 pf[4];                                                                      \
    _Pragma("unroll") for (int g = 0; g < 4; ++g) {                                 \
        const f32x16& Sh = (g & 2) ? S1 : S0;                                       \
        const int kk = g & 1;                                                       \
        _Pragma("unroll") for (int mm = 0; mm < 4; ++mm) {                          \
            float ea = __builtin_amdgcn_exp2f(Sh[kk * 8 + 2 * mm]);                 \
            float eb = __builtin_amdgcn_exp2f(Sh[kk * 8 + 2 * mm + 1]);             \
            psum += ea + eb;                                                        \
            pf[g].u[mm] = pk2(ea, eb);                                              \
        }                                                                           \
    }                                                                               \
    _Pragma("unroll") for (int gi = 2; gi < 4; ++gi)                                \
      _Pragma("unroll") for (int dc = 0; dc < 4; ++dc)                              \
        vr[gi][dc] = *(const bf16x8*)(vp0 + (size_t)gi * (DIMH * 16) + dc * 32 * 16);\
    if (DO_QK) {                                                                    \
        S0 = (f32x16){}; S1 = (f32x16){};                                           \
        _Pragma("unroll") for (int kc = 0; kc < 8; ++kc) {                          \
            bf16x8 k0 = *(const bf16x8*)&Ks[rd + c31 * KSTR + kc * 16 + h * 8];     \
            bf16x8 k1 = *(const bf16x8*)&Ks[rd + (32 + c31) * KSTR + kc * 16 + h * 8]; \
            S0 = MFMA32(k0, qf[kc], S0);                                            \
            S1 = MFMA32(k1, qf[kc], S1);                                            \
        }                                                                           \
    }                                                                               \
    _Pragma("unroll") for (int g = 0; g < 4; ++g)                                   \
        _Pragma("unroll") for (int dc = 0; dc < 4; ++dc)                            \
            O[dc] = MFMA32(vr[g][dc], pf[g].v, O[dc]);                              \
    if (DO_PRE) {                                                                   \
        _Pragma("unroll") for (int p = 0; p < 4; ++p)                               \
            *(int4*)&Ks[wr + l * KSTR + (p * 4 + w) * 8] = kreg[p];                 \
    }                                                                               \
    if (DO_BAR) __syncthreads();                                                    \
}

__global__ __launch_bounds__(256, 2) void attn(
    const short* __restrict__ Q, const short* __restrict__ Kf,
    const short* __restrict__ Vf, float* __restrict__ out)
{
    __shared__ short Ks[2 * BJ * KSTR];   // double-buffered K tile [j][c]

    const int t = threadIdx.x, l = t & 63, w = t >> 6;
    const int h = l >> 5, c31 = l & 31;

    const int L = blockIdx.x;
    const int x = L & 7, inner = L >> 3;          // XCD swizzle: same bh -> same XCD
    const int bh = x * 8 + (inner >> 3);
    const int q0 = (inner & 7) * BQ;
    const size_t obase = (size_t)bh * DIMH * SEQ;

    // Q B-fragments (n = i = q0+w*32+c31, k = c = kc*16 + h*8 + 0..7)
    bf16x8 qf[8];
    {
        const short* Qp = Q + ((size_t)bh * SEQ + (q0 + w * 32 + c31)) * DIMH + h * 8;
        #pragma unroll
        for (int kc = 0; kc < 8; ++kc)
            qf[kc] = *(const bf16x8*)(Qp + kc * 16);
    }

    const short* Kg = Kf + (size_t)bh * 16 * SEQ * 8;             // [cg][s][8]
    const short* Vlane = Vf + (size_t)bh * 64 * (DIMH * 16) + (c31 * 16 + h * 8);

    f32x16 O[4] = {};
    float psum = 0.f;

    // prologue: stage K(0) -> slot0, K(1) -> slot1
    {
        int4 k0[4], k1[4];
        #pragma unroll
        for (int p = 0; p < 4; ++p) {
            k0[p] = *(const int4*)(Kg + ((size_t)(p * 4 + w) * SEQ + l) * 8);
            k1[p] = *(const int4*)(Kg + ((size_t)(p * 4 + w) * SEQ + BJ + l) * 8);
        }
        #pragma unroll
        for (int p = 0; p < 4; ++p) {
            *(int4*)&Ks[l * KSTR + (p * 4 + w) * 8] = k0[p];
            *(int4*)&Ks[BJ * KSTR + l * KSTR + (p * 4 + w) * 8] = k1[p];
        }
    }
    __syncthreads();

    // S(0) from slot0
    f32x16 S0 = {}, S1 = {};
    #pragma unroll
    for (int kc = 0; kc < 8; ++kc) {
        bf16x8 k0 = *(const bf16x8*)&Ks[c31 * KSTR + kc * 16 + h * 8];
        bf16x8 k1 = *(const bf16x8*)&Ks[(32 + c31) * KSTR + kc * 16 + h * 8];
        S0 = MFMA32(k0, qf[kc], S0);
        S1 = MFMA32(k1, qf[kc], S1);
    }
    __syncthreads();   // all waves done reading slot0 before iter0 overwrites it

    for (int p = 0; p < 7; ++p) {
        const int t0 = 2 * p;
        ATTN_ITER(t0,     true, true, true);
        ATTN_ITER(t0 + 1, true, true, true);
    }
    ATTN_ITER(14, true,  false, false);
    ATTN_ITER(15, false, false, false);

    // row sum: this lane holds half the j's for row i=c31; other half in lane^32
    psum += __shfl_xor(psum, 32);
    float linv = 1.0f / psum;

    #pragma unroll
    for (int dc = 0; dc < 4; ++dc)
        #pragma unroll
        for (int r = 0; r < 16; ++r) {
            int d = dc * 32 + (r & 3) + 8 * (r >> 2) + 4 * h;
            out[obase + (size_t)d * SEQ + q0 + w * 32 + c31] = O[dc][r] * linv;
        }
}

extern "C" void kernel_launch(void* const* d_in, const int* in_sizes, int n_in,
                              void* d_out, int out_size, void* d_ws, size_t ws_size,
                              hipStream_t stream) {
    const float* fmap   = (const float*)d_in[0];
    const float* w_qkv  = (const float*)d_in[1];
    const float* height = (const float*)d_in[2];
    const float* width  = (const float*)d_in[3];
    float* outp = (float*)d_out;

    const size_t n_ft  = (size_t)NB * SEQ * CIN;
    const size_t n_w   = (size_t)OTOT * CIN;
    const size_t n_qkv = (size_t)NB * HEADS * SEQ * DIMH;

    short* FT2 = (short*)d_ws;
    short* Wb2 = FT2 + n_ft;
    short* Qb  = Wb2 + n_w;
    short* Kfb = Qb + n_qkv;
    short* Vfb = Kfb + n_qkv;

    convert_all<<<dim3(6, KQ, NB + 1), 256, 0, stream>>>(fmap, w_qkv, FT2, Wb2);
    qkv_gemm<<<dim3(8 * 12 * NB), 256, 0, stream>>>(
        Wb2, FT2, height, width, Qb, Kfb, Vfb);
    attn<<<dim3(NB * HEADS * (SEQ / BQ)), 256, 0, stream>>>(Qb, Kfb, Vfb, outp);
}